// Round 12
// baseline (348.668 us; speedup 1.0000x reference)
//
#include <hip/hip_runtime.h>

#define DEV __device__ __forceinline__

typedef __attribute__((ext_vector_type(8))) short short8v;
typedef __attribute__((ext_vector_type(4))) float f32x4;

DEV unsigned short f2bf(float f) {
  unsigned int x = __float_as_uint(f);
  x = x + 0x7FFFu + ((x >> 16) & 1u);   // RNE
  return (unsigned short)(x >> 16);
}
DEV float bf2f(unsigned short u) {
  return __uint_as_float(((unsigned)u) << 16);
}

// ---- swizzled LDS tile, BK=64: row stride 128 B, 8x16B chunks (0 confl) ----
DEV int swz_byte(int row, int kElem) {
  int chunk = ((kElem >> 3) ^ (row & 7));
  return row * 128 + (chunk << 4) + ((kElem & 7) << 1);
}

// Stage ROUNDS*32 rows x 64 cols of bf16 (256-thread kernels), BK=64 swizzle.
template <int ROUNDS>
DEV void stage(const unsigned short* __restrict__ g, int ld,
               unsigned short* tile, int tid) {
  const int wave = tid >> 6, l = tid & 63;
#pragma unroll
  for (int p = 0; p < ROUNDS; ++p) {
    const int r = (p << 5) + (wave << 3) + (l >> 3);
    const int c = ((l & 7) ^ (r & 7)) << 3;              // pre-swizzled col
    const unsigned short* src = g + (long)r * ld + c;
#if __has_builtin(__builtin_amdgcn_global_load_lds)
    unsigned short* dst = tile + (p << 11) + (wave << 9);  // wave-uniform
    __builtin_amdgcn_global_load_lds(
        (const __attribute__((address_space(1))) void*)src,
        (__attribute__((address_space(3))) void*)dst, 16, 0, 0);
#else
    short8v v = *reinterpret_cast<const short8v*>(src);
    *reinterpret_cast<short8v*>(reinterpret_cast<char*>(tile) +
                                (p << 12) + (wave << 10) + (l << 4)) = v;
#endif
  }
}

// Reg-staged fp32 -> bf16 A-staging: BM rows x 64 cols.
template <int BM>
DEV void stage_f32(const float* __restrict__ g, int ld,
                   unsigned short* tile, int tid) {
  const int rl = tid >> 4;           // 0..15
  const int c4 = (tid & 15) << 2;    // 0,4,...,60
#pragma unroll
  for (int p = 0; p < BM / 16; ++p) {
    const int row = (p << 4) + rl;
    const float4 f = *reinterpret_cast<const float4*>(g + (long)row * ld + c4);
    ushort4 pack;
    pack.x = f2bf(f.x); pack.y = f2bf(f.y); pack.z = f2bf(f.z); pack.w = f2bf(f.w);
    *reinterpret_cast<ushort4*>(reinterpret_cast<char*>(tile) +
                                swz_byte(row, c4)) = pack;
  }
}

// NT GEMM: C[M][N] = A[M][K] * B[N][K]^T. Tile BM x 128, BK=64.
// EPI: 0 -> bf16; 2 -> masked raw scores BF16 + stats.
// GM : 0: (x=nt, y=mt, z=z); 1: 1-D batch->XCD swizzle (scores);
//      2: (x=mt, y=nt, z=z).
// AF32: A operand is fp32, converted during reg-staging.
template <int BM, int EPI, int GM, bool AF32>
__global__ __launch_bounds__(256) void gemm_bf16(
    const void* __restrict__ Av, const unsigned short* __restrict__ B,
    void* __restrict__ Cout, int M, int N, int K,
    long aBatch, long bBatch, long cBatch,
    const int* __restrict__ srcMask, const int* __restrict__ melMask,
    float scale, float* __restrict__ stats) {
  constexpr int NI = BM / 32;
  __shared__ unsigned short As[BM * 64];
  __shared__ unsigned short Bs[128 * 64];
  const int tid = threadIdx.x;
  const int lane = tid & 63;
  const int wave = tid >> 6;
  int z, bmi, bni;
  if constexpr (GM == 1) {
    const int id = blockIdx.x;            // 16z x 16nt x 8mt = 2048
    z = (id & 7) | ((id >> 10) << 3);
    const int ib = (id >> 3) & 127;
    bni = ib & 15;
    bmi = ib >> 4;
  } else if constexpr (GM == 2) {
    bmi = blockIdx.x; bni = blockIdx.y; z = blockIdx.z;
  } else {
    bni = blockIdx.x; bmi = blockIdx.y; z = blockIdx.z;
  }
  const int bm = bmi * BM;
  const int bn = bni * 128;
  const unsigned short* Bb = B + (long)z * bBatch;
  const long cOff = (long)z * cBatch;
  const int wr = (wave >> 1) * (BM / 2);
  const int wc = (wave & 1) * 64;
  const int l15 = lane & 15;
  const int lHi = lane >> 4;

  f32x4 acc[NI][4] = {};

  for (int kt = 0; kt < K; kt += 64) {
    if constexpr (AF32) {
      stage_f32<BM>((const float*)Av + (long)z * aBatch + (long)bm * K + kt, K, As, tid);
    } else {
      stage<BM / 32>((const unsigned short*)Av + (long)z * aBatch + (long)bm * K + kt,
                     K, As, tid);
    }
    stage<4>(Bb + (long)bn * K + kt, K, Bs, tid);
    __syncthreads();
#pragma unroll
    for (int ks = 0; ks < 2; ++ks) {
      const int k0 = (ks << 5) + (lHi << 3);
      short8v af[NI], bfr[4];
#pragma unroll
      for (int i = 0; i < NI; ++i)
        af[i] = *reinterpret_cast<const short8v*>(
            reinterpret_cast<const char*>(As) + swz_byte(wr + i * 16 + l15, k0));
#pragma unroll
      for (int j = 0; j < 4; ++j)
        bfr[j] = *reinterpret_cast<const short8v*>(
            reinterpret_cast<const char*>(Bs) + swz_byte(wc + j * 16 + l15, k0));
#pragma unroll
      for (int i = 0; i < NI; ++i)
#pragma unroll
        for (int j = 0; j < 4; ++j)
          acc[i][j] = __builtin_amdgcn_mfma_f32_16x16x32_bf16(af[i], bfr[j], acc[i][j], 0, 0, 0);
    }
    __syncthreads();
  }

  if constexpr (EPI == 2) {
    __shared__ float redM[128][2];
    __shared__ float redS[128][2];
    const int wcIdx = wave & 1;
#pragma unroll
    for (int i = 0; i < NI; ++i) {
#pragma unroll
      for (int rr = 0; rr < 4; ++rr) {
        const int rloc = wr + i * 16 + lHi * 4 + rr;
        const int rb = bm + rloc;
        const bool sm = srcMask[z * 1024 + rb] != 0;
        float vals[4];
        float m_l = -3.0e38f;
#pragma unroll
        for (int j = 0; j < 4; ++j) {
          const int c = bn + wc + j * 16 + l15;
          const bool mm = melMask[z * 2048 + c] != 0;
          const float vf = (sm && mm) ? -1e30f : acc[i][j][rr] * scale;
          vals[j] = vf;
          reinterpret_cast<unsigned short*>(Cout)[cOff + (long)rb * N + c] = f2bf(vf);
          m_l = fmaxf(m_l, vf);
        }
#pragma unroll
        for (int o = 1; o < 16; o <<= 1) m_l = fmaxf(m_l, __shfl_xor(m_l, o, 64));
        float s_l = 0.f;
#pragma unroll
        for (int j = 0; j < 4; ++j) s_l += __expf(vals[j] - m_l);
#pragma unroll
        for (int o = 1; o < 16; o <<= 1) s_l += __shfl_xor(s_l, o, 64);
        if (l15 == 0) { redM[rloc][wcIdx] = m_l; redS[rloc][wcIdx] = s_l; }
      }
    }
    __syncthreads();
    if (tid < 128) {
      const float m0 = redM[tid][0], m1 = redM[tid][1];
      const float Mx = fmaxf(m0, m1);
      const float S = redS[tid][0] * __expf(m0 - Mx) + redS[tid][1] * __expf(m1 - Mx);
      const long sidx = ((long)(z * 1024 + bm + tid)) * 32 + (long)bni * 2;
      stats[sidx] = Mx;
      stats[sidx + 1] = S;
    }
  } else {
#pragma unroll
    for (int i = 0; i < NI; ++i) {
#pragma unroll
      for (int j = 0; j < 4; ++j) {
        const int rb = bm + wr + i * 16 + lHi * 4;
        const int c = bn + wc + j * 16 + l15;
#pragma unroll
        for (int r = 0; r < 4; ++r) {
          const long idx = cOff + (long)(rb + r) * N + c;
          reinterpret_cast<unsigned short*>(Cout)[idx] = f2bf(acc[i][j][r]);
        }
      }
    }
  }
}

// Fused softmax + PV, PURE REGISTER fragments: no LDS tiles, no K-loop
// barriers. A (scores) and B (vT) loaded 16 B/lane directly from global in
// MFMA fragment layout; exp/normalize in-register; wc==0 waves write the
// block's kt-quarter of normalized attn fp32 (exactly-once).
// BM=64 x BN=128 per block (wave = 32x64). 1-D grid 1024, z->XCD co-located.
__global__ __launch_bounds__(256) void pv_reg(
    const unsigned short* __restrict__ sbf, const unsigned short* __restrict__ vT,
    float* __restrict__ attn, float* __restrict__ out,
    const float* __restrict__ stats) {
  __shared__ float rowM[64], rowInv[64];
  const int id = blockIdx.x;
  const int z = (id & 7) | ((id >> 9) << 3);
  const int ib = (id >> 3) & 63;
  const int mt = ib & 15, nt = ib >> 4;
  const int bm = mt * 64, bn = nt * 128;
  const int tid = threadIdx.x, lane = tid & 63, wave = tid >> 6;

  if (tid < 64) {
    const float* st = stats + ((long)(z * 1024 + bm + tid)) * 32;
    float Mx = -3.0e38f;
#pragma unroll
    for (int t = 0; t < 16; ++t) Mx = fmaxf(Mx, st[t * 2]);
    float S = 0.f;
#pragma unroll
    for (int t = 0; t < 16; ++t) S += st[t * 2 + 1] * __expf(st[t * 2] - Mx);
    rowM[tid] = Mx;
    rowInv[tid] = 1.0f / S;
  }
  __syncthreads();

  const int wr = (wave >> 1) * 32, wc = (wave & 1) * 64;
  const int l15 = lane & 15, lHi = lane >> 4;
  const int r0 = wr + l15, r1 = wr + 16 + l15;       // this lane's A rows
  const float m0 = rowM[r0], v0 = rowInv[r0];
  const float m1 = rowM[r1], v1 = rowInv[r1];
  const int k8 = lHi << 3;                            // lane's 8-elem k window
  const unsigned short* a0 = sbf + ((long)(z * 1024 + bm + r0)) * 2048 + k8;
  const unsigned short* a1 = sbf + ((long)(z * 1024 + bm + r1)) * 2048 + k8;
  const unsigned short* b0 =
      vT + ((long)(z * 512 + bn + wc + l15)) * 2048 + k8;
  float* at0 = attn + ((long)(z * 1024 + bm + r0)) * 2048 + k8;
  float* at1 = attn + ((long)(z * 1024 + bm + r1)) * 2048 + k8;
  const bool ownA = (wave & 1) == 0;                  // wc==0 waves write attn
  const int ktlo = nt << 9, kthi = (nt + 1) << 9;

  f32x4 acc[2][4] = {};

#pragma unroll 2
  for (int kt = 0; kt < 2048; kt += 32) {
    const short8v sa0 = *reinterpret_cast<const short8v*>(a0 + kt);
    const short8v sa1 = *reinterpret_cast<const short8v*>(a1 + kt);
    short8v bfr[4];
#pragma unroll
    for (int j = 0; j < 4; ++j)
      bfr[j] = *reinterpret_cast<const short8v*>(b0 + (long)j * 16 * 2048 + kt);

    float e0[8], e1[8];
#pragma unroll
    for (int u = 0; u < 8; ++u) {
      e0[u] = __expf(bf2f((unsigned short)sa0[u]) - m0) * v0;
      e1[u] = __expf(bf2f((unsigned short)sa1[u]) - m1) * v1;
    }
    if (ownA && kt >= ktlo && kt < kthi) {
      float4 w;
      w.x = e0[0]; w.y = e0[1]; w.z = e0[2]; w.w = e0[3];
      *reinterpret_cast<float4*>(at0 + kt) = w;
      w.x = e0[4]; w.y = e0[5]; w.z = e0[6]; w.w = e0[7];
      *reinterpret_cast<float4*>(at0 + kt + 4) = w;
      w.x = e1[0]; w.y = e1[1]; w.z = e1[2]; w.w = e1[3];
      *reinterpret_cast<float4*>(at1 + kt) = w;
      w.x = e1[4]; w.y = e1[5]; w.z = e1[6]; w.w = e1[7];
      *reinterpret_cast<float4*>(at1 + kt + 4) = w;
    }
    short8v p0, p1;
#pragma unroll
    for (int u = 0; u < 8; ++u) {
      p0[u] = (short)f2bf(e0[u]);
      p1[u] = (short)f2bf(e1[u]);
    }
#pragma unroll
    for (int j = 0; j < 4; ++j) {
      acc[0][j] = __builtin_amdgcn_mfma_f32_16x16x32_bf16(p0, bfr[j], acc[0][j], 0, 0, 0);
      acc[1][j] = __builtin_amdgcn_mfma_f32_16x16x32_bf16(p1, bfr[j], acc[1][j], 0, 0, 0);
    }
  }

#pragma unroll
  for (int i = 0; i < 2; ++i)
#pragma unroll
    for (int j = 0; j < 4; ++j) {
      const int row = bm + wr + i * 16 + lHi * 4;
      const int col = bn + wc + j * 16 + l15;
#pragma unroll
      for (int rr = 0; rr < 4; ++rr)
        out[((long)z * 1024 + row + rr) * 512 + col] = acc[i][j][rr];
    }
}

// fp32 -> bf16 elementwise, 8 elems/thread, grid-stride.
__global__ __launch_bounds__(256) void f32_to_bf16(
    const float* __restrict__ in, unsigned short* __restrict__ out, long n) {
  long i = ((long)blockIdx.x * blockDim.x + threadIdx.x) * 8;
  const long stride = (long)gridDim.x * blockDim.x * 8;
  for (; i < n; i += stride) {
    const float4 a = *reinterpret_cast<const float4*>(in + i);
    const float4 b = *reinterpret_cast<const float4*>(in + i + 4);
    short8v o;
    o[0] = (short)f2bf(a.x); o[1] = (short)f2bf(a.y);
    o[2] = (short)f2bf(a.z); o[3] = (short)f2bf(a.w);
    o[4] = (short)f2bf(b.x); o[5] = (short)f2bf(b.y);
    o[6] = (short)f2bf(b.z); o[7] = (short)f2bf(b.w);
    *reinterpret_cast<short8v*>(out + i) = o;
  }
}

// Merged weight prep: z=0 transpose+convert Wv -> WvT; z=1 convert Wq;
// z=2 convert Wk. Grid (16,16,3), block (32,8).
__global__ __launch_bounds__(256) void prep_w(
    const float* __restrict__ Wq, const float* __restrict__ Wk,
    const float* __restrict__ Wv, unsigned short* __restrict__ wqbf,
    unsigned short* __restrict__ wkbf, unsigned short* __restrict__ WvT) {
  const int zz = blockIdx.z;
  const int tx = threadIdx.x, ty = threadIdx.y;
  if (zz == 0) {
    __shared__ float t[32][33];
    const int bx = blockIdx.x * 32;
    const int by = blockIdx.y * 32;
#pragma unroll
    for (int i = 0; i < 4; ++i)
      t[ty + i * 8][tx] = Wv[(long)(by + ty + i * 8) * 512 + bx + tx];
    __syncthreads();
#pragma unroll
    for (int i = 0; i < 4; ++i)
      WvT[(long)(bx + ty + i * 8) * 512 + by + tx] = f2bf(t[tx][ty + i * 8]);
  } else {
    const float* in = (zz == 1) ? Wq : Wk;
    unsigned short* out = (zz == 1) ? wqbf : wkbf;
    const long base = ((long)(blockIdx.y * 16 + blockIdx.x) * 256 + ty * 32 + tx) * 4;
    const float4 f = *reinterpret_cast<const float4*>(in + base);
    ushort4 o;
    o.x = f2bf(f.x); o.y = f2bf(f.y); o.z = f2bf(f.z); o.w = f2bf(f.w);
    *reinterpret_cast<ushort4*>(out + base) = o;
  }
}

// In-place LayerNorm over rows of 512 fp32. One wave per row.
__global__ __launch_bounds__(64) void layernorm_rows(
    float* __restrict__ out, const float* __restrict__ gamma, const float* __restrict__ beta) {
  const long row = blockIdx.x;
  float4* p = reinterpret_cast<float4*>(out + row * 512);
  const int lane = threadIdx.x;
  float4 a = p[lane];
  float4 b = p[lane + 64];
  float s = ((a.x + a.y) + (a.z + a.w)) + ((b.x + b.y) + (b.z + b.w));
  float s2 = ((a.x * a.x + a.y * a.y) + (a.z * a.z + a.w * a.w)) +
             ((b.x * b.x + b.y * b.y) + (b.z * b.z + b.w * b.w));
#pragma unroll
  for (int o = 32; o; o >>= 1) {
    s += __shfl_xor(s, o, 64);
    s2 += __shfl_xor(s2, o, 64);
  }
  const float mean = s * (1.0f / 512.0f);
  const float var = s2 * (1.0f / 512.0f) - mean * mean;
  const float rstd = rsqrtf(var + 1e-5f);
  const float4 g0 = reinterpret_cast<const float4*>(gamma)[lane];
  const float4 g1 = reinterpret_cast<const float4*>(gamma)[lane + 64];
  const float4 c0 = reinterpret_cast<const float4*>(beta)[lane];
  const float4 c1 = reinterpret_cast<const float4*>(beta)[lane + 64];
  a.x = (a.x - mean) * rstd * g0.x + c0.x;
  a.y = (a.y - mean) * rstd * g0.y + c0.y;
  a.z = (a.z - mean) * rstd * g0.z + c0.z;
  a.w = (a.w - mean) * rstd * g0.w + c0.w;
  b.x = (b.x - mean) * rstd * g1.x + c1.x;
  b.y = (b.y - mean) * rstd * g1.y + c1.y;
  b.z = (b.z - mean) * rstd * g1.z + c1.z;
  b.w = (b.w - mean) * rstd * g1.w + c1.w;
  p[lane] = a;
  p[lane + 64] = b;
}

extern "C" void kernel_launch(void* const* d_in, const int* in_sizes, int n_in,
                              void* d_out, int out_size, void* d_ws, size_t ws_size,
                              hipStream_t stream) {
  const float* mel  = (const float*)d_in[0];   // [16,2048,512]
  const float* text = (const float*)d_in[1];   // [16,1024,512]
  const int* melMask = (const int*)d_in[2];    // [16,2048]
  const int* srcMask = (const int*)d_in[3];    // [16,1024]
  const float* Wq = (const float*)d_in[4];
  const float* Wk = (const float*)d_in[5];
  const float* Wv = (const float*)d_in[6];
  const float* gamma = (const float*)d_in[7];
  const float* beta  = (const float*)d_in[8];

  float* out = (float*)d_out;                           // [16,1024,512]
  float* attn = (float*)d_out + (long)16 * 1024 * 512;  // [16,1024,2048]

  unsigned short* ws = (unsigned short*)d_ws;
  unsigned short* wqbf = ws;                              // 512*512
  unsigned short* wkbf = wqbf + 512 * 512;
  unsigned short* wvT  = wkbf + 512 * 512;
  unsigned short* Mt   = wvT + 512 * 512;                 // (Wq Wk^T)^T bf16
  unsigned short* melbf = Mt + 512 * 512;                 // 16*2048*512
  unsigned short* qbf  = melbf + (long)16 * 2048 * 512;   // 16*1024*512
  unsigned short* vT   = qbf + (long)16 * 1024 * 512;     // 16*512*2048
  unsigned short* sbf  = vT + (long)16 * 512 * 2048;      // 16*1024*2048
  float* stats = (float*)(sbf + (long)16 * 1024 * 2048);  // 16*1024*16*2 f32
  // total ~155 MB

  // weight prep (merged) + mel conversion
  prep_w<<<dim3(16, 16, 3), dim3(32, 8), 0, stream>>>(Wq, Wk, Wv, wqbf, wkbf, wvT);
  f32_to_bf16<<<dim3(4096), 256, 0, stream>>>(mel, melbf, (long)16 * 2048 * 512);

  // Mt[e][d] = sum_m Wk[e][m]*Wq[d][m]  == (Wq Wk^T)^T
  gemm_bf16<128, 0, 0, false><<<dim3(4, 4, 1), 256, 0, stream>>>(
      wkbf, wqbf, Mt, 512, 512, 512, 0, 0, 0, nullptr, nullptr, 1.0f, nullptr);
  // q' = text @ Mt^T (fp32 A converted in staging)
  gemm_bf16<128, 0, 2, true><<<dim3(128, 4, 1), 256, 0, stream>>>(
      text, Mt, qbf, 16384, 512, 512, 0, 0, 0, nullptr, nullptr, 1.0f, nullptr);
  // vT[m][s] = sum_d WvT[m][d]*mel[s][d]
  gemm_bf16<128, 0, 0, false><<<dim3(16, 4, 16), 256, 0, stream>>>(
      wvT, melbf, vT, 512, 2048, 512, 0, (long)2048 * 512, (long)512 * 2048,
      nullptr, nullptr, 1.0f, nullptr);
  // raw masked scores (bf16) + stats; B = melbf directly (k folded into q')
  gemm_bf16<128, 2, 1, false><<<dim3(2048), 256, 0, stream>>>(
      qbf, melbf, sbf, 1024, 2048, 512,
      (long)1024 * 512, (long)2048 * 512, (long)1024 * 2048,
      srcMask, melMask, 0.044194173824159216f, stats);
  // fused softmax(+balanced attn write) + PV, pure-register, barrier-free
  pv_reg<<<dim3(1024), 256, 0, stream>>>(sbf, vT, attn, out, stats);
  layernorm_rows<<<dim3(16 * 1024), 64, 0, stream>>>(out, gamma, beta);
}

// Round 13
// 259.255 us; speedup vs baseline: 1.3449x; 1.3449x over previous
//
#include <hip/hip_runtime.h>

#define DEV __device__ __forceinline__

typedef __attribute__((ext_vector_type(8))) short short8v;
typedef __attribute__((ext_vector_type(4))) float f32x4;

DEV unsigned short f2bf(float f) {
  unsigned int x = __float_as_uint(f);
  x = x + 0x7FFFu + ((x >> 16) & 1u);   // RNE
  return (unsigned short)(x >> 16);
}
DEV float bf2f(unsigned short u) {
  return __uint_as_float(((unsigned)u) << 16);
}

// ---- swizzled LDS tile, BK=64: row stride 128 B, 8x16B chunks (0 confl) ----
DEV int swz_byte(int row, int kElem) {
  int chunk = ((kElem >> 3) ^ (row & 7));
  return row * 128 + (chunk << 4) + ((kElem & 7) << 1);
}

// Stage ROUNDS*32 rows x 64 cols of bf16 (256-thread kernels), BK=64 swizzle.
template <int ROUNDS>
DEV void stage(const unsigned short* __restrict__ g, int ld,
               unsigned short* tile, int tid) {
  const int wave = tid >> 6, l = tid & 63;
#pragma unroll
  for (int p = 0; p < ROUNDS; ++p) {
    const int r = (p << 5) + (wave << 3) + (l >> 3);
    const int c = ((l & 7) ^ (r & 7)) << 3;              // pre-swizzled col
    const unsigned short* src = g + (long)r * ld + c;
#if __has_builtin(__builtin_amdgcn_global_load_lds)
    unsigned short* dst = tile + (p << 11) + (wave << 9);  // wave-uniform
    __builtin_amdgcn_global_load_lds(
        (const __attribute__((address_space(1))) void*)src,
        (__attribute__((address_space(3))) void*)dst, 16, 0, 0);
#else
    short8v v = *reinterpret_cast<const short8v*>(src);
    *reinterpret_cast<short8v*>(reinterpret_cast<char*>(tile) +
                                (p << 12) + (wave << 10) + (l << 4)) = v;
#endif
  }
}

// Reg-staged fp32 -> bf16 A-staging: BM rows x 64 cols.
template <int BM>
DEV void stage_f32(const float* __restrict__ g, int ld,
                   unsigned short* tile, int tid) {
  const int rl = tid >> 4;           // 0..15
  const int c4 = (tid & 15) << 2;    // 0,4,...,60
#pragma unroll
  for (int p = 0; p < BM / 16; ++p) {
    const int row = (p << 4) + rl;
    const float4 f = *reinterpret_cast<const float4*>(g + (long)row * ld + c4);
    ushort4 pack;
    pack.x = f2bf(f.x); pack.y = f2bf(f.y); pack.z = f2bf(f.z); pack.w = f2bf(f.w);
    *reinterpret_cast<ushort4*>(reinterpret_cast<char*>(tile) +
                                swz_byte(row, c4)) = pack;
  }
}

// NT GEMM: C[M][N] = A[M][K] * B[N][K]^T. Tile BM x 128, BK=64.
// EPI: 0 -> bf16; 2 -> masked scores, stored as PTILDE = exp(s - m_half)
//      (bf16) + per-(row, 64-col-half) stats (m_half, sum-exp).
// GM : 0: (x=nt, y=mt, z=z); 1: 1-D batch->XCD swizzle (scores);
//      2: (x=mt, y=nt, z=z).
// AF32: A operand is fp32, converted during reg-staging.
template <int BM, int EPI, int GM, bool AF32>
__global__ __launch_bounds__(256) void gemm_bf16(
    const void* __restrict__ Av, const unsigned short* __restrict__ B,
    void* __restrict__ Cout, int M, int N, int K,
    long aBatch, long bBatch, long cBatch,
    const int* __restrict__ srcMask, const int* __restrict__ melMask,
    float scale, float* __restrict__ stats) {
  constexpr int NI = BM / 32;
  __shared__ unsigned short As[BM * 64];
  __shared__ unsigned short Bs[128 * 64];
  const int tid = threadIdx.x;
  const int lane = tid & 63;
  const int wave = tid >> 6;
  int z, bmi, bni;
  if constexpr (GM == 1) {
    const int id = blockIdx.x;            // 16z x 16nt x 8mt = 2048
    z = (id & 7) | ((id >> 10) << 3);
    const int ib = (id >> 3) & 127;
    bni = ib & 15;
    bmi = ib >> 4;
  } else if constexpr (GM == 2) {
    bmi = blockIdx.x; bni = blockIdx.y; z = blockIdx.z;
  } else {
    bni = blockIdx.x; bmi = blockIdx.y; z = blockIdx.z;
  }
  const int bm = bmi * BM;
  const int bn = bni * 128;
  const unsigned short* Bb = B + (long)z * bBatch;
  const long cOff = (long)z * cBatch;
  const int wr = (wave >> 1) * (BM / 2);
  const int wc = (wave & 1) * 64;
  const int l15 = lane & 15;
  const int lHi = lane >> 4;

  f32x4 acc[NI][4] = {};

  for (int kt = 0; kt < K; kt += 64) {
    if constexpr (AF32) {
      stage_f32<BM>((const float*)Av + (long)z * aBatch + (long)bm * K + kt, K, As, tid);
    } else {
      stage<BM / 32>((const unsigned short*)Av + (long)z * aBatch + (long)bm * K + kt,
                     K, As, tid);
    }
    stage<4>(Bb + (long)bn * K + kt, K, Bs, tid);
    __syncthreads();
#pragma unroll
    for (int ks = 0; ks < 2; ++ks) {
      const int k0 = (ks << 5) + (lHi << 3);
      short8v af[NI], bfr[4];
#pragma unroll
      for (int i = 0; i < NI; ++i)
        af[i] = *reinterpret_cast<const short8v*>(
            reinterpret_cast<const char*>(As) + swz_byte(wr + i * 16 + l15, k0));
#pragma unroll
      for (int j = 0; j < 4; ++j)
        bfr[j] = *reinterpret_cast<const short8v*>(
            reinterpret_cast<const char*>(Bs) + swz_byte(wc + j * 16 + l15, k0));
#pragma unroll
      for (int i = 0; i < NI; ++i)
#pragma unroll
        for (int j = 0; j < 4; ++j)
          acc[i][j] = __builtin_amdgcn_mfma_f32_16x16x32_bf16(af[i], bfr[j], acc[i][j], 0, 0, 0);
    }
    __syncthreads();
  }

  if constexpr (EPI == 2) {
    const int wcIdx = wave & 1;
#pragma unroll
    for (int i = 0; i < NI; ++i) {
#pragma unroll
      for (int rr = 0; rr < 4; ++rr) {
        const int rloc = wr + i * 16 + lHi * 4 + rr;
        const int rb = bm + rloc;
        const bool sm = srcMask[z * 1024 + rb] != 0;
        float vals[4];
        float m_l = -3.0e38f;
#pragma unroll
        for (int j = 0; j < 4; ++j) {
          const int c = bn + wc + j * 16 + l15;
          const bool mm = melMask[z * 2048 + c] != 0;
          const float vf = (sm && mm) ? -1e30f : acc[i][j][rr] * scale;
          vals[j] = vf;
          m_l = fmaxf(m_l, vf);
        }
#pragma unroll
        for (int o = 1; o < 16; o <<= 1) m_l = fmaxf(m_l, __shfl_xor(m_l, o, 64));
        float s_l = 0.f;
#pragma unroll
        for (int j = 0; j < 4; ++j) {
          const float pe = __expf(vals[j] - m_l);   // ptilde (masked -> 0)
          s_l += pe;
          const int c = bn + wc + j * 16 + l15;
          reinterpret_cast<unsigned short*>(Cout)[cOff + (long)rb * N + c] = f2bf(pe);
        }
#pragma unroll
        for (int o = 1; o < 16; o <<= 1) s_l += __shfl_xor(s_l, o, 64);
        if (l15 == 0) {
          // per-half stats: [row][32 halves][2] (m, sum-exp)
          const long sidx = ((long)(z * 1024 + rb)) * 64 + (long)(bni * 2 + wcIdx) * 2;
          stats[sidx] = m_l;
          stats[sidx + 1] = s_l;
        }
      }
    }
  } else {
#pragma unroll
    for (int i = 0; i < NI; ++i) {
#pragma unroll
      for (int j = 0; j < 4; ++j) {
        const int rb = bm + wr + i * 16 + lHi * 4;
        const int c = bn + wc + j * 16 + l15;
#pragma unroll
        for (int r = 0; r < 4; ++r) {
          const long idx = cOff + (long)(rb + r) * N + c;
          reinterpret_cast<unsigned short*>(Cout)[idx] = f2bf(acc[i][j][r]);
        }
      }
    }
  }
}

// Fused softmax + PV, BK=128 per iteration as two 64-subtiles. EXP-FREE loop:
// sbf holds ptilde = exp(s - m_half); per-(row, half) scale table precomputed
// at block start -> loop A-transform is a single mul + pack.
// BM=64 x BN=128, 256 thr, ~52.5 KB LDS -> 3 blocks/CU.
// Block nt writes normalized attn fp32 for kt in [nt*512,(nt+1)*512).
// 1-D grid 1024 (16z x 16mt x 4nt), batch->XCD co-located.
__global__ __launch_bounds__(256) void pv_smx(
    const unsigned short* __restrict__ sbf, const unsigned short* __restrict__ vT,
    float* __restrict__ attn, float* __restrict__ out,
    const float* __restrict__ stats) {
  __shared__ unsigned short As[2][64 * 64];    // 2 x 8 KB
  __shared__ unsigned short Bs[2][128 * 64];   // 2 x 16 KB
  __shared__ unsigned short scl[64][32];       // bf16 scale/(row, 64-half), 4 KB
  const int id = blockIdx.x;
  const int z = (id & 7) | ((id >> 9) << 3);
  const int ib = (id >> 3) & 63;
  const int mt = ib & 15, nt = ib >> 4;
  const int bm = mt * 64, bn = nt * 128;
  const int tid = threadIdx.x, lane = tid & 63, wave = tid >> 6;

  // per-row combine (4 threads/row, redundant) + scale table (8 halves each)
  {
    const int row = tid >> 2;
    const float* st = stats + ((long)(z * 1024 + bm + row)) * 64;
    float Mx = -3.0e38f;
#pragma unroll
    for (int t = 0; t < 32; ++t) Mx = fmaxf(Mx, st[t * 2]);
    float S = 0.f;
#pragma unroll
    for (int t = 0; t < 32; ++t) S += st[t * 2 + 1] * __expf(st[t * 2] - Mx);
    const float inv = 1.0f / S;
    const int t0 = (tid & 3) * 8;
#pragma unroll
    for (int t = 0; t < 8; ++t)
      scl[row][t0 + t] = f2bf(__expf(st[(t0 + t) * 2] - Mx) * inv);
  }
  __syncthreads();

  const int ar = tid >> 2;               // A row 0..63 (4 thr/row)
  const int ac = (tid & 3) << 4;         // 16 elems per thread per half
  const long aOff = ((long)z * 1024 + bm + ar) * 2048 + ac;
  const unsigned short* vTb = vT + ((long)z * 512 + bn) * 2048;
  const int wr = (wave >> 1) * 32, wc = (wave & 1) * 64;
  const int l15 = lane & 15, lHi = lane >> 4;

  f32x4 acc[2][4] = {};

  for (int it = 0; it < 16; ++it) {
    const int kt = it << 7;              // 128-wide step
    stage<4>(vTb + kt, 2048, Bs[0], tid);
    stage<4>(vTb + kt + 64, 2048, Bs[1], tid);
    // A: two 64-halves, ptilde * scale -> bf16 swizzled LDS (+ attn if owner)
#pragma unroll
    for (int h = 0; h < 2; ++h) {
      const int kh = kt + (h << 6);
      const float sc = bf2f(scl[ar][kh >> 6]);
      const short8v s0 = *reinterpret_cast<const short8v*>(sbf + aOff + kh);
      const short8v s1 = *reinterpret_cast<const short8v*>(sbf + aOff + kh + 8);
      float e[16];
#pragma unroll
      for (int u = 0; u < 8; ++u) {
        e[u] = bf2f((unsigned short)s0[u]) * sc;
        e[u + 8] = bf2f((unsigned short)s1[u]) * sc;
      }
      if ((kh >> 9) == nt) {             // balanced exactly-once attn write
        float* ap = attn + aOff + kh;
#pragma unroll
        for (int g = 0; g < 4; ++g) {
          float4 w;
          w.x = e[g * 4]; w.y = e[g * 4 + 1]; w.z = e[g * 4 + 2]; w.w = e[g * 4 + 3];
          *reinterpret_cast<float4*>(ap + g * 4) = w;
        }
      }
      short8v pk0, pk1;
#pragma unroll
      for (int u = 0; u < 8; ++u) {
        pk0[u] = (short)f2bf(e[u]);
        pk1[u] = (short)f2bf(e[u + 8]);
      }
      *reinterpret_cast<short8v*>(reinterpret_cast<char*>(As[h]) + swz_byte(ar, ac)) = pk0;
      *reinterpret_cast<short8v*>(reinterpret_cast<char*>(As[h]) + swz_byte(ar, ac + 8)) = pk1;
    }
    __syncthreads();

#pragma unroll
    for (int h = 0; h < 2; ++h) {
#pragma unroll
      for (int ks = 0; ks < 2; ++ks) {
        const int k0 = (ks << 5) + (lHi << 3);
        short8v af[2], bfr[4];
#pragma unroll
        for (int i = 0; i < 2; ++i)
          af[i] = *reinterpret_cast<const short8v*>(
              reinterpret_cast<const char*>(As[h]) + swz_byte(wr + i * 16 + l15, k0));
#pragma unroll
        for (int j = 0; j < 4; ++j)
          bfr[j] = *reinterpret_cast<const short8v*>(
              reinterpret_cast<const char*>(Bs[h]) + swz_byte(wc + j * 16 + l15, k0));
#pragma unroll
        for (int i = 0; i < 2; ++i)
#pragma unroll
          for (int j = 0; j < 4; ++j)
            acc[i][j] = __builtin_amdgcn_mfma_f32_16x16x32_bf16(af[i], bfr[j], acc[i][j], 0, 0, 0);
      }
    }
    __syncthreads();
  }

#pragma unroll
  for (int i = 0; i < 2; ++i)
#pragma unroll
    for (int j = 0; j < 4; ++j) {
      const int row = bm + wr + i * 16 + lHi * 4;
      const int col = bn + wc + j * 16 + l15;
#pragma unroll
      for (int rr = 0; rr < 4; ++rr)
        out[((long)z * 1024 + row + rr) * 512 + col] = acc[i][j][rr];
    }
}

// fp32 -> bf16 elementwise, 8 elems/thread, grid-stride.
__global__ __launch_bounds__(256) void f32_to_bf16(
    const float* __restrict__ in, unsigned short* __restrict__ out, long n) {
  long i = ((long)blockIdx.x * blockDim.x + threadIdx.x) * 8;
  const long stride = (long)gridDim.x * blockDim.x * 8;
  for (; i < n; i += stride) {
    const float4 a = *reinterpret_cast<const float4*>(in + i);
    const float4 b = *reinterpret_cast<const float4*>(in + i + 4);
    short8v o;
    o[0] = (short)f2bf(a.x); o[1] = (short)f2bf(a.y);
    o[2] = (short)f2bf(a.z); o[3] = (short)f2bf(a.w);
    o[4] = (short)f2bf(b.x); o[5] = (short)f2bf(b.y);
    o[6] = (short)f2bf(b.z); o[7] = (short)f2bf(b.w);
    *reinterpret_cast<short8v*>(out + i) = o;
  }
}

// Merged weight prep: z=0 transpose+convert Wv -> WvT; z=1 convert Wq;
// z=2 convert Wk. Grid (16,16,3), block (32,8).
__global__ __launch_bounds__(256) void prep_w(
    const float* __restrict__ Wq, const float* __restrict__ Wk,
    const float* __restrict__ Wv, unsigned short* __restrict__ wqbf,
    unsigned short* __restrict__ wkbf, unsigned short* __restrict__ WvT) {
  const int zz = blockIdx.z;
  const int tx = threadIdx.x, ty = threadIdx.y;
  if (zz == 0) {
    __shared__ float t[32][33];
    const int bx = blockIdx.x * 32;
    const int by = blockIdx.y * 32;
#pragma unroll
    for (int i = 0; i < 4; ++i)
      t[ty + i * 8][tx] = Wv[(long)(by + ty + i * 8) * 512 + bx + tx];
    __syncthreads();
#pragma unroll
    for (int i = 0; i < 4; ++i)
      WvT[(long)(bx + ty + i * 8) * 512 + by + tx] = f2bf(t[tx][ty + i * 8]);
  } else {
    const float* in = (zz == 1) ? Wq : Wk;
    unsigned short* out = (zz == 1) ? wqbf : wkbf;
    const long base = ((long)(blockIdx.y * 16 + blockIdx.x) * 256 + ty * 32 + tx) * 4;
    const float4 f = *reinterpret_cast<const float4*>(in + base);
    ushort4 o;
    o.x = f2bf(f.x); o.y = f2bf(f.y); o.z = f2bf(f.z); o.w = f2bf(f.w);
    *reinterpret_cast<ushort4*>(out + base) = o;
  }
}

// In-place LayerNorm over rows of 512 fp32. One wave per row.
__global__ __launch_bounds__(64) void layernorm_rows(
    float* __restrict__ out, const float* __restrict__ gamma, const float* __restrict__ beta) {
  const long row = blockIdx.x;
  float4* p = reinterpret_cast<float4*>(out + row * 512);
  const int lane = threadIdx.x;
  float4 a = p[lane];
  float4 b = p[lane + 64];
  float s = ((a.x + a.y) + (a.z + a.w)) + ((b.x + b.y) + (b.z + b.w));
  float s2 = ((a.x * a.x + a.y * a.y) + (a.z * a.z + a.w * a.w)) +
             ((b.x * b.x + b.y * b.y) + (b.z * b.z + b.w * b.w));
#pragma unroll
  for (int o = 32; o; o >>= 1) {
    s += __shfl_xor(s, o, 64);
    s2 += __shfl_xor(s2, o, 64);
  }
  const float mean = s * (1.0f / 512.0f);
  const float var = s2 * (1.0f / 512.0f) - mean * mean;
  const float rstd = rsqrtf(var + 1e-5f);
  const float4 g0 = reinterpret_cast<const float4*>(gamma)[lane];
  const float4 g1 = reinterpret_cast<const float4*>(gamma)[lane + 64];
  const float4 c0 = reinterpret_cast<const float4*>(beta)[lane];
  const float4 c1 = reinterpret_cast<const float4*>(beta)[lane + 64];
  a.x = (a.x - mean) * rstd * g0.x + c0.x;
  a.y = (a.y - mean) * rstd * g0.y + c0.y;
  a.z = (a.z - mean) * rstd * g0.z + c0.z;
  a.w = (a.w - mean) * rstd * g0.w + c0.w;
  b.x = (b.x - mean) * rstd * g1.x + c1.x;
  b.y = (b.y - mean) * rstd * g1.y + c1.y;
  b.z = (b.z - mean) * rstd * g1.z + c1.z;
  b.w = (b.w - mean) * rstd * g1.w + c1.w;
  p[lane] = a;
  p[lane + 64] = b;
}

extern "C" void kernel_launch(void* const* d_in, const int* in_sizes, int n_in,
                              void* d_out, int out_size, void* d_ws, size_t ws_size,
                              hipStream_t stream) {
  const float* mel  = (const float*)d_in[0];   // [16,2048,512]
  const float* text = (const float*)d_in[1];   // [16,1024,512]
  const int* melMask = (const int*)d_in[2];    // [16,2048]
  const int* srcMask = (const int*)d_in[3];    // [16,1024]
  const float* Wq = (const float*)d_in[4];
  const float* Wk = (const float*)d_in[5];
  const float* Wv = (const float*)d_in[6];
  const float* gamma = (const float*)d_in[7];
  const float* beta  = (const float*)d_in[8];

  float* out = (float*)d_out;                           // [16,1024,512]
  float* attn = (float*)d_out + (long)16 * 1024 * 512;  // [16,1024,2048]

  unsigned short* ws = (unsigned short*)d_ws;
  unsigned short* wqbf = ws;                              // 512*512
  unsigned short* wkbf = wqbf + 512 * 512;
  unsigned short* wvT  = wkbf + 512 * 512;
  unsigned short* Mt   = wvT + 512 * 512;                 // (Wq Wk^T)^T bf16
  unsigned short* melbf = Mt + 512 * 512;                 // 16*2048*512
  unsigned short* qbf  = melbf + (long)16 * 2048 * 512;   // 16*1024*512
  unsigned short* vT   = qbf + (long)16 * 1024 * 512;     // 16*512*2048
  unsigned short* sbf  = vT + (long)16 * 512 * 2048;      // 16*1024*2048
  float* stats = (float*)(sbf + (long)16 * 1024 * 2048);  // [16*1024][32][2] f32, 4 MB
  // total ~157 MB

  // weight prep (merged) + mel conversion
  prep_w<<<dim3(16, 16, 3), dim3(32, 8), 0, stream>>>(Wq, Wk, Wv, wqbf, wkbf, wvT);
  f32_to_bf16<<<dim3(4096), 256, 0, stream>>>(mel, melbf, (long)16 * 2048 * 512);

  // Mt[e][d] = sum_m Wk[e][m]*Wq[d][m]  == (Wq Wk^T)^T
  gemm_bf16<128, 0, 0, false><<<dim3(4, 4, 1), 256, 0, stream>>>(
      wkbf, wqbf, Mt, 512, 512, 512, 0, 0, 0, nullptr, nullptr, 1.0f, nullptr);
  // q' = text @ Mt^T (fp32 A converted in staging)
  gemm_bf16<128, 0, 2, true><<<dim3(128, 4, 1), 256, 0, stream>>>(
      text, Mt, qbf, 16384, 512, 512, 0, 0, 0, nullptr, nullptr, 1.0f, nullptr);
  // vT[m][s] = sum_d WvT[m][d]*mel[s][d]
  gemm_bf16<128, 0, 0, false><<<dim3(16, 4, 16), 256, 0, stream>>>(
      wvT, melbf, vT, 512, 2048, 512, 0, (long)2048 * 512, (long)512 * 2048,
      nullptr, nullptr, 1.0f, nullptr);
  // masked scores -> ptilde (bf16) + per-half stats; B = melbf (k folded)
  gemm_bf16<128, 2, 1, false><<<dim3(2048), 256, 0, stream>>>(
      qbf, melbf, sbf, 1024, 2048, 512,
      (long)1024 * 512, (long)2048 * 512, (long)1024 * 2048,
      srcMask, melMask, 0.044194173824159216f, stats);
  // fused softmax(+balanced attn write) + PV, exp-free loop
  pv_smx<<<dim3(1024), 256, 0, stream>>>(sbf, vT, attn, out, stats);
  layernorm_rows<<<dim3(16 * 1024), 64, 0, stream>>>(out, gamma, beta);
}